// Round 22
// baseline (248.197 us; speedup 1.0000x reference)
//
#include <hip/hip_runtime.h>
#include <hip/hip_bf16.h>
#include <math.h>

typedef unsigned short ushort_t;
typedef unsigned char uchar_t;
typedef __attribute__((ext_vector_type(8))) short short8;
typedef __attribute__((ext_vector_type(4))) float f32x4;
typedef __attribute__((ext_vector_type(2))) float f32x2;
typedef __attribute__((ext_vector_type(4))) unsigned short u16x4;

#define LOG2E 1.44269504088896f

static __device__ __forceinline__ float b2f(ushort_t u) {
    union { unsigned int i; float f; } v; v.i = ((unsigned int)u) << 16; return v.f;
}
static __device__ __forceinline__ ushort_t f2b(float f) {
    unsigned int x = __float_as_uint(f);
    unsigned int r = (x + 0x7fffu + ((x >> 16) & 1u)) >> 16;
    return (ushort_t)r;
}
static __device__ __forceinline__ uchar_t f2e4m3(float f) {
    int r = __builtin_amdgcn_cvt_pk_fp8_f32(f, f, 0, false);
    return (uchar_t)(r & 0xff);
}
static __device__ __forceinline__ float exp2fast(float x) {
    return __builtin_amdgcn_exp2f(x);     // v_exp_f32 (2^x)
}

// ---------------- merged prologue: conv W1/W2, build wa1/wa2, pad rows, zero deg ----------------

template<int K, int Cd>
static __device__ void wa_item(const float* __restrict__ W, const float* __restrict__ as,
                               const float* __restrict__ ad, ushort_t* __restrict__ Bext,
                               int rowoff, int tid) {
    int col = tid / K, k = tid - col * K;
    const float* a = (col < 8) ? as : ad;
    int h = col & 7;
    float s = 0.f;
    #pragma unroll 4
    for (int c = 0; c < Cd; ++c)
        s += W[(size_t)(h * Cd + c) * K + k] * a[h * Cd + c];
    Bext[(size_t)(rowoff + col) * K + k] = f2b(s * LOG2E);
}

__global__ void prep_kernel(const float* __restrict__ W1, const float* __restrict__ W2,
                            const float* __restrict__ as1, const float* __restrict__ ad1,
                            const float* __restrict__ as2, const float* __restrict__ ad2,
                            ushort_t* __restrict__ w1b, ushort_t* __restrict__ w2b,
                            float* als1, float* als2, uchar_t* h1f8, uchar_t* h2f8,
                            int* __restrict__ deg, int n) {
    int b = blockIdx.x, t = threadIdx.x;
    if (b < 40) {                     // conv W1 (8192 f4) + W2 (20480 f4)
        for (int i = b * 256 + t; i < 8192 + 20480; i += 40 * 256) {
            if (i < 8192) {
                float4 v = *(const float4*)(W1 + i * 4);
                u16x4 o = { f2b(v.x), f2b(v.y), f2b(v.z), f2b(v.w) };
                *(u16x4*)(w1b + i * 4) = o;
            } else {
                int j = i - 8192;
                float4 v = *(const float4*)(W2 + j * 4);
                u16x4 o = { f2b(v.x), f2b(v.y), f2b(v.z), f2b(v.w) };
                *(u16x4*)(w2b + j * 4) = o;
            }
        }
    } else if (b < 64) {              // wa1 (2048 items) + wa2 (4096 items)
        for (int i = (b - 40) * 256 + t; i < 2048 + 4096; i += 24 * 256) {
            if (i < 2048) wa_item<128, 32>(W1, as1, ad1, w1b, 256, i);
            else          wa_item<256, 40>(W2, as2, ad2, w2b, 320, i - 2048);
        }
    } else if (b == 64) {             // pads (sentinel row n)
        if (t < 8) { als1[(size_t)n * 8 + t] = -1e30f; als2[(size_t)n * 8 + t] = -1e30f; }
        h1f8[(size_t)n * 256 + t] = 0;
        h2f8[(size_t)n * 320 + t] = 0;
        if (t < 64) h2f8[(size_t)n * 320 + 256 + t] = 0;
    } else {                          // zero deg
        int i = (b - 65) * 256 + t;
        if (i < n) deg[i] = 0;
    }
}

// ---------------- merged conv_x + degree count ----------------

__global__ void convx_count_kernel(const float* __restrict__ x, ushort_t* __restrict__ xb, int n4x,
                                   const int* __restrict__ ei, int E, int n, int* __restrict__ deg) {
    int b = blockIdx.x, t = threadIdx.x;
    if (b < 2048) {
        for (int i = b * 256 + t; i < n4x; i += 2048 * 256) {
            float4 v = *(const float4*)(x + i * 4);
            u16x4 o = { f2b(v.x), f2b(v.y), f2b(v.z), f2b(v.w) };
            *(u16x4*)(xb + i * 4) = o;
        }
    } else {
        int e = (b - 2048) * 256 + t;
        int Etot = E + n;
        if (e < Etot) {
            int dst = (e < E) ? ei[E + e] : (e - E);
            atomicAdd(&deg[dst], 1);
        }
    }
}

// ---------------- CSR build: 3-phase parallel scan; scan_write also prefills sentinels ----------------

__global__ void scan_part_kernel(const int* __restrict__ deg, int* __restrict__ bsum, int n) {
    int i = blockIdx.x * 256 + threadIdx.x;
    int v = (i < n) ? ((deg[i] + 7) & ~7) : 0;
    #pragma unroll
    for (int off = 1; off < 64; off <<= 1) v += __shfl_xor(v, off);
    __shared__ int ws[4];
    int wid = threadIdx.x >> 6, lane = threadIdx.x & 63;
    if (lane == 0) ws[wid] = v;
    __syncthreads();
    if (threadIdx.x == 0) bsum[blockIdx.x] = ws[0] + ws[1] + ws[2] + ws[3];
}

__global__ void scan_top_kernel(int* __restrict__ bsum, int nb) {
    int t = threadIdx.x;
    int v = (t < nb) ? bsum[t] : 0;
    int val = v;
    int lane = t & 63, wid = t >> 6;
    #pragma unroll
    for (int off = 1; off < 64; off <<= 1) {
        int nv = __shfl_up(val, off);
        if (lane >= off) val += nv;
    }
    __shared__ int ws[4];
    if (lane == 63) ws[wid] = val;
    __syncthreads();
    int pre = 0;
    for (int w = 0; w < 4; ++w) if (w < wid) pre += ws[w];
    if (t < nb) bsum[t] = pre + val - v;
}

__global__ void scan_write_kernel(const int* __restrict__ deg, const int* __restrict__ bsum,
                                  int* __restrict__ rowptr, int* __restrict__ cursor,
                                  int* __restrict__ ssrc, int n) {
    int i = blockIdx.x * 256 + threadIdx.x;
    int t = threadIdx.x;
    int v = (i < n) ? ((deg[i] + 7) & ~7) : 0;
    int val = v;
    int lane = t & 63, wid = t >> 6;
    #pragma unroll
    for (int off = 1; off < 64; off <<= 1) {
        int nv = __shfl_up(val, off);
        if (lane >= off) val += nv;
    }
    __shared__ int ws[4];
    if (lane == 63) ws[wid] = val;
    __syncthreads();
    int pre = bsum[blockIdx.x];
    for (int w = 0; w < 4; ++w) if (w < wid) pre += ws[w];
    int excl = pre + val - v;
    if (i < n) {
        rowptr[i] = excl; cursor[i] = excl;
        for (int p = excl; p < excl + v; ++p) ssrc[p] = n;   // sentinel prefill; scatter overwrites
    }
    if (i == n - 1) rowptr[n] = excl + v;
}

__global__ void scatter_kernel(const int* __restrict__ ei, int E, int n,
                               int* __restrict__ cursor, int* __restrict__ ssrc) {
    int e = blockIdx.x * blockDim.x + threadIdx.x;
    int Etot = E + n;
    if (e >= Etot) return;
    int src, dst;
    if (e < E) { src = ei[e]; dst = ei[E + e]; }
    else       { src = e - E; dst = e - E; }
    int pos = atomicAdd(&cursor[dst], 1);
    ssrc[pos] = src;
}

// ---------------- bf16 MFMA NT GEMM + fused attention logits, fp8 feature output ----------------
// BM = 128 (8 waves x 16 rows), single accumulator set (known-good config).

template<int NFRAG, int K>
__global__ __launch_bounds__(512) void gemm_lds_al(const ushort_t* __restrict__ A,
                                                   const ushort_t* __restrict__ B,
                                                   uchar_t* __restrict__ C,
                                                   float* __restrict__ als,
                                                   float* __restrict__ ald, int M) {
    constexpr int N = NFRAG * 16;
    constexpr int NOUT = (NFRAG - 1) * 16;
    constexpr int RS = 40;                 // LDS row stride in elems
    constexpr int NK = K / 32;
    __shared__ ushort_t Bs[2][N * RS];
    const int t = threadIdx.x;
    const int w = t >> 6, l = t & 63;
    const int r0 = blockIdx.x * 128 + w * 16;
    int arow = r0 + (l & 15);
    if (arow >= M) arow = M - 1;
    const int koff = (l >> 4) * 8;
    const ushort_t* ap = A + (size_t)arow * K + koff;

    f32x4 acc[NFRAG];
    #pragma unroll
    for (int i = 0; i < NFRAG; ++i) acc[i] = (f32x4){0.f, 0.f, 0.f, 0.f};

    auto stage = [&](int buf, int k0) {
        #pragma unroll
        for (int c = t; c < N * 4; c += 512) {
            int row = c >> 2, part = (c & 3) << 3;           // part in elems
            *(short8*)&Bs[buf][row * RS + part] =
                *(const short8*)(B + (size_t)row * K + k0 + part);
        }
    };

    stage(0, 0);
    __syncthreads();
    #pragma unroll
    for (int kk = 0; kk < NK; ++kk) {
        int buf = kk & 1;
        if (kk + 1 < NK) stage(buf ^ 1, (kk + 1) * 32);
        short8 a = *(const short8*)(ap + kk * 32);
        #pragma unroll
        for (int nf = 0; nf < NFRAG; ++nf) {
            short8 b = *(const short8*)&Bs[buf][(nf * 16 + (l & 15)) * RS + koff];
            acc[nf] = __builtin_amdgcn_mfma_f32_16x16x32_bf16(a, b, acc[nf], 0, 0, 0);
        }
        __syncthreads();
    }

    const int crow0 = r0 + (l >> 4) * 4;
    #pragma unroll
    for (int nf = 0; nf < NFRAG - 1; ++nf) {
        #pragma unroll
        for (int j = 0; j < 4; ++j) {
            int row = crow0 + j;
            if (row < M) C[(size_t)row * NOUT + nf * 16 + (l & 15)] = f2e4m3(acc[nf][j]);
        }
    }
    {   // attention-logit fragment (pre-scaled by log2e)
        int col = l & 15;
        float* dstp = (col < 8) ? als : ald;
        int h = col & 7;
        #pragma unroll
        for (int j = 0; j < 4; ++j) {
            int row = crow0 + j;
            if (row < M) dstp[(size_t)row * 8 + h] = acc[NFRAG - 1][j];
        }
    }
}

// ---------------- layer-1 aggregation: weight-lane specialization + half-wave fp8 gather ----------------
// weight role (all 64 lanes): ew = l&7 (edge slot), hw = l>>3 (head) -> one weight per 8-edge iter.
// feature role: half = l>>5, ll = l&31 (8B of row, head hd = ll>>2); weights via shuffle.

__device__ __forceinline__ float lrelu(float e) { return (e > 0.f) ? e : 0.2f * e; }

__global__ void agg1_kernel(const uchar_t* __restrict__ h1, const float* __restrict__ als,
                            const float* __restrict__ aldv, const float* __restrict__ b1,
                            const int* __restrict__ rowptr, const int* __restrict__ ssrc,
                            ushort_t* __restrict__ hout, int n) {
    int node = blockIdx.x * 4 + (threadIdx.x >> 6);
    if (node >= n) return;
    int l = threadIdx.x & 63;
    // weight role
    int ew = l & 7, hw = l >> 3;
    float aldw = aldv[node * 8 + hw];
    // feature role
    int half = l >> 5, ll = l & 31;
    int hd = ll >> 2;
    int wsel = hd * 8 + half * 4;          // weight-lane base for my half's edges
    int beg = rowptr[node], end = rowptr[node + 1];
    float wacc = 0.f;
    f32x2 a0 = {0.f, 0.f}, a1 = {0.f, 0.f}, a2 = {0.f, 0.f}, a3 = {0.f, 0.f};
    const uchar_t* fb = h1 + ll * 8;
    for (int p = beg; p < end; p += 8) {
        int sw = ssrc[p + ew];
        float wv = exp2fast(lrelu(als[sw * 8 + hw] + aldw));
        wacc += wv;
        int4 s4 = *(const int4*)(ssrc + p + half * 4);
        uint2 g0 = *(const uint2*)(fb + (size_t)s4.x * 256);
        uint2 g1 = *(const uint2*)(fb + (size_t)s4.y * 256);
        uint2 g2 = *(const uint2*)(fb + (size_t)s4.z * 256);
        uint2 g3 = *(const uint2*)(fb + (size_t)s4.w * 256);
        float w0 = __shfl(wv, wsel + 0), w1 = __shfl(wv, wsel + 1);
        float w2 = __shfl(wv, wsel + 2), w3 = __shfl(wv, wsel + 3);
        #define DQ(g, wv_) { \
            f32x2 q0 = __builtin_amdgcn_cvt_pk_f32_fp8((int)g.x, false); \
            f32x2 q1 = __builtin_amdgcn_cvt_pk_f32_fp8((int)g.x, true);  \
            f32x2 q2 = __builtin_amdgcn_cvt_pk_f32_fp8((int)g.y, false); \
            f32x2 q3 = __builtin_amdgcn_cvt_pk_f32_fp8((int)g.y, true);  \
            f32x2 w2v = {wv_, wv_}; \
            a0 += w2v * q0; a1 += w2v * q1; a2 += w2v * q2; a3 += w2v * q3; }
        DQ(g0, w0) DQ(g1, w1) DQ(g2, w2) DQ(g3, w3)
        #undef DQ
    }
    // den per head from weight role (covers all 8 edge slots)
    wacc += __shfl_xor(wacc, 1);
    wacc += __shfl_xor(wacc, 2);
    wacc += __shfl_xor(wacc, 4);
    float den = __shfl(wacc, hd * 8);
    // merge accumulator halves (lane ^ 32)
    a0.x += __shfl_xor(a0.x, 32); a0.y += __shfl_xor(a0.y, 32);
    a1.x += __shfl_xor(a1.x, 32); a1.y += __shfl_xor(a1.y, 32);
    a2.x += __shfl_xor(a2.x, 32); a2.y += __shfl_xor(a2.y, 32);
    a3.x += __shfl_xor(a3.x, 32); a3.y += __shfl_xor(a3.y, 32);
    if (half == 0) {
        float inv = 1.f / den;
        float4 bv0 = *(const float4*)(b1 + ll * 8);
        float4 bv1 = *(const float4*)(b1 + ll * 8 + 4);
        float v0 = a0.x * inv + bv0.x, v1 = a0.y * inv + bv0.y;
        float v2 = a1.x * inv + bv0.z, v3 = a1.y * inv + bv0.w;
        float v4 = a2.x * inv + bv1.x, v5 = a2.y * inv + bv1.y;
        float v6 = a3.x * inv + bv1.z, v7 = a3.y * inv + bv1.w;
        u16x4 o0, o1;
        o0.x = f2b((v0 > 0.f) ? v0 : __expf(v0) - 1.f);
        o0.y = f2b((v1 > 0.f) ? v1 : __expf(v1) - 1.f);
        o0.z = f2b((v2 > 0.f) ? v2 : __expf(v2) - 1.f);
        o0.w = f2b((v3 > 0.f) ? v3 : __expf(v3) - 1.f);
        o1.x = f2b((v4 > 0.f) ? v4 : __expf(v4) - 1.f);
        o1.y = f2b((v5 > 0.f) ? v5 : __expf(v5) - 1.f);
        o1.z = f2b((v6 > 0.f) ? v6 : __expf(v6) - 1.f);
        o1.w = f2b((v7 > 0.f) ? v7 : __expf(v7) - 1.f);
        ushort_t* op = hout + (size_t)node * 256 + ll * 8;
        *(u16x4*)op = o0;
        *(u16x4*)(op + 4) = o1;
    }
}

// ---------------- layer-2 aggregation: weight-lane specialization + fp8 gather ----------------

__global__ void agg2_kernel(const uchar_t* __restrict__ h2, const float* __restrict__ als,
                            const float* __restrict__ aldv, const float* __restrict__ b2,
                            const int* __restrict__ rowptr, const int* __restrict__ ssrc,
                            float* __restrict__ out, int n) {
    int node = blockIdx.x * 4 + (threadIdx.x >> 6);
    if (node >= n) return;
    int l = threadIdx.x & 63;
    // weight role
    int ew = l & 7, hw = l >> 3;
    float aldw = aldv[node * 8 + hw];
    // feature role
    int li = (l < 40) ? l : 0;
    int hd = li / 5;
    int cg = li - hd * 5;
    int wbase = hd * 8;                    // lane holding (hd, e=0)
    int beg = rowptr[node], end = rowptr[node + 1];
    const uchar_t* base = h2 + hd * 40 + cg * 8;
    float wacc = 0.f;
    f32x2 acc01 = {0.f, 0.f}, acc23 = {0.f, 0.f}, acc45 = {0.f, 0.f}, acc67 = {0.f, 0.f};
    for (int p = beg; p < end; p += 8) {
        int sw = ssrc[p + ew];
        float wv = exp2fast(lrelu(als[sw * 8 + hw] + aldw));
        wacc += wv;
        int4 sA = *(const int4*)(ssrc + p);
        int4 sB = *(const int4*)(ssrc + p + 4);
        uint2 g0 = *(const uint2*)(base + (size_t)sA.x * 320);
        uint2 g1 = *(const uint2*)(base + (size_t)sA.y * 320);
        uint2 g2 = *(const uint2*)(base + (size_t)sA.z * 320);
        uint2 g3 = *(const uint2*)(base + (size_t)sA.w * 320);
        uint2 g4 = *(const uint2*)(base + (size_t)sB.x * 320);
        uint2 g5 = *(const uint2*)(base + (size_t)sB.y * 320);
        uint2 g6 = *(const uint2*)(base + (size_t)sB.z * 320);
        uint2 g7 = *(const uint2*)(base + (size_t)sB.w * 320);
        float w0 = __shfl(wv, wbase + 0), w1 = __shfl(wv, wbase + 1);
        float w2 = __shfl(wv, wbase + 2), w3 = __shfl(wv, wbase + 3);
        float w4 = __shfl(wv, wbase + 4), w5 = __shfl(wv, wbase + 5);
        float w6 = __shfl(wv, wbase + 6), w7 = __shfl(wv, wbase + 7);
        #define DQ(g, wv_) { \
            f32x2 q0 = __builtin_amdgcn_cvt_pk_f32_fp8((int)g.x, false); \
            f32x2 q1 = __builtin_amdgcn_cvt_pk_f32_fp8((int)g.x, true);  \
            f32x2 q2 = __builtin_amdgcn_cvt_pk_f32_fp8((int)g.y, false); \
            f32x2 q3 = __builtin_amdgcn_cvt_pk_f32_fp8((int)g.y, true);  \
            f32x2 w2v = {wv_, wv_}; \
            acc01 += w2v * q0; acc23 += w2v * q1; \
            acc45 += w2v * q2; acc67 += w2v * q3; }
        DQ(g0, w0) DQ(g1, w1) DQ(g2, w2) DQ(g3, w3)
        DQ(g4, w4) DQ(g5, w5) DQ(g6, w6) DQ(g7, w7)
        #undef DQ
    }
    wacc += __shfl_xor(wacc, 1);
    wacc += __shfl_xor(wacc, 2);
    wacc += __shfl_xor(wacc, 4);
    float den = __shfl(wacc, wbase);
    float inv = 1.f / den;
    float v[8] = {acc01.x * inv, acc01.y * inv, acc23.x * inv, acc23.y * inv,
                  acc45.x * inv, acc45.y * inv, acc67.x * inv, acc67.y * inv};
    #pragma unroll
    for (int j = 0; j < 8; ++j) {
        float s = v[j];
        s += __shfl_down(s, 20);
        s += __shfl_down(s, 10);
        s += __shfl_down(s, 5);
        v[j] = s;
    }
    if (l < 5) {
        float wv[8];
        #pragma unroll
        for (int j = 0; j < 8; ++j) wv[j] = 0.125f * v[j] + b2[l * 8 + j];
        float m8 = wv[0];
        #pragma unroll
        for (int j = 1; j < 8; ++j) m8 = fmaxf(m8, wv[j]);
        float mx = m8;
        #pragma unroll
        for (int k = 0; k < 5; ++k) mx = fmaxf(mx, __shfl(m8, k));
        float se8 = 0.f;
        #pragma unroll
        for (int j = 0; j < 8; ++j) se8 += __expf(wv[j] - mx);
        float se = 0.f;
        #pragma unroll
        for (int k = 0; k < 5; ++k) se += __shfl(se8, k);
        float lse = mx + __logf(se);
        float* op = out + (size_t)node * 40 + l * 8;
        float4 o0 = {wv[0] - lse, wv[1] - lse, wv[2] - lse, wv[3] - lse};
        float4 o1 = {wv[4] - lse, wv[5] - lse, wv[6] - lse, wv[7] - lse};
        *(float4*)op = o0;
        *(float4*)(op + 4) = o1;
    }
}

// ---------------- launch ----------------

extern "C" void kernel_launch(void* const* d_in, const int* in_sizes, int n_in,
                              void* d_out, int out_size, void* d_ws, size_t ws_size,
                              hipStream_t stream) {
    const float* x      = (const float*)d_in[0];
    const int*   ei     = (const int*)d_in[1];
    const float* W1     = (const float*)d_in[2];
    const float* a_src1 = (const float*)d_in[3];
    const float* a_dst1 = (const float*)d_in[4];
    const float* b1     = (const float*)d_in[5];
    const float* W2     = (const float*)d_in[6];
    const float* a_src2 = (const float*)d_in[7];
    const float* a_dst2 = (const float*)d_in[8];
    const float* b2     = (const float*)d_in[9];
    float* out = (float*)d_out;

    const int n    = in_sizes[0] / 128;   // 50000
    const int E    = in_sizes[1] / 2;     // 800000
    const int Etot = E + n;
    const int EpM  = Etot + 7 * n + 16;   // upper bound on padded edge count
    const int nb   = (n + 255) / 256;     // scan blocks

    char* w = (char*)d_ws;
    auto take = [&](size_t bytes) {
        char* p = w;
        w += (bytes + 255) & ~(size_t)255;
        return p;
    };
    int*      deg    = (int*)take((size_t)n * 4);
    int*      rowptr = (int*)take((size_t)(n + 1) * 4);
    int*      cursor = (int*)take((size_t)n * 4);
    int*      bsum   = (int*)take((size_t)(nb + 1) * 4);
    int*      ssrc   = (int*)take((size_t)EpM * 4);
    ushort_t* xb     = (ushort_t*)take((size_t)n * 128 * 2);
    ushort_t* w1b    = (ushort_t*)take((size_t)272 * 128 * 2);   // 256 W1 rows + 16 wa rows
    ushort_t* w2b    = (ushort_t*)take((size_t)336 * 256 * 2);   // 320 W2 rows + 16 wa rows
    uchar_t*  h1f8   = (uchar_t*)take((size_t)(n + 1) * 256);
    ushort_t* helu   = (ushort_t*)take((size_t)n * 256 * 2);
    uchar_t*  h2f8   = (uchar_t*)take((size_t)(n + 1) * 320);
    float*    als1   = (float*)take((size_t)(n + 1) * 8 * 4);
    float*    ald1   = (float*)take((size_t)n * 8 * 4);
    float*    als2   = (float*)take((size_t)(n + 1) * 8 * 4);
    float*    ald2   = (float*)take((size_t)n * 8 * 4);

    // merged prologue (W converts + wa folds + sentinel pads + deg zero)
    prep_kernel<<<65 + nb, 256, 0, stream>>>(W1, W2, a_src1, a_dst1, a_src2, a_dst2,
                                             w1b, w2b, als1, als2, h1f8, h2f8, deg, n);

    // merged x-convert + degree count, then CSR (3-phase parallel scan, sentinel prefill)
    int eb = (Etot + 255) / 256;
    convx_count_kernel<<<2048 + eb, 256, 0, stream>>>(x, xb, n * 128 / 4, ei, E, n, deg);
    scan_part_kernel<<<nb, 256, 0, stream>>>(deg, bsum, n);
    scan_top_kernel<<<1, 256, 0, stream>>>(bsum, nb);
    scan_write_kernel<<<nb, 256, 0, stream>>>(deg, bsum, rowptr, cursor, ssrc, n);
    scatter_kernel<<<eb, 256, 0, stream>>>(ei, E, n, cursor, ssrc);

    int gb = (n + 127) / 128;
    int nb4 = (n + 3) / 4;

    // layer 1 (gemm computes fp8 h1 AND f32 als1/ald1)
    gemm_lds_al<17, 128><<<gb, 512, 0, stream>>>(xb, w1b, h1f8, als1, ald1, n);
    agg1_kernel<<<nb4, 256, 0, stream>>>(h1f8, als1, ald1, b1, rowptr, ssrc, helu, n);

    // layer 2
    gemm_lds_al<21, 256><<<gb, 512, 0, stream>>>(helu, w2b, h2f8, als2, ald2, n);
    agg2_kernel<<<nb4, 256, 0, stream>>>(h2f8, als2, ald2, b2, rowptr, ssrc, out, n);
}